// Round 3
// baseline (468.439 us; speedup 1.0000x reference)
//
#include <hip/hip_runtime.h>

typedef __attribute__((ext_vector_type(8))) short short8;
typedef __attribute__((ext_vector_type(4))) float f32x4;

__device__ __forceinline__ float bf2f(unsigned short u){
  return __uint_as_float(((unsigned int)u) << 16);
}
__device__ __forceinline__ unsigned short f2bf(float f){
  unsigned int u = __float_as_uint(f);
  u += 0x7fffu + ((u >> 16) & 1u);   // RNE
  return (unsigned short)(u >> 16);
}
// dtype-dispatching scalar load: isF32 ? f32[i] : bf16[i]
__device__ __forceinline__ float ldf(const void* p, long i, int isF32){
  return isF32 ? ((const float*)p)[i] : bf2f(((const unsigned short*)p)[i]);
}

// ---- prep: dtype detect (block 0) + row_ptr from sorted rows ----
__global__ void prep_k(const int* __restrict__ rows, int* __restrict__ rs,
                       int E, int N, const unsigned short* __restrict__ x,
                       int* __restrict__ flag){
  if (blockIdx.x == 0){
    __shared__ int s;
    if (threadIdx.x == 0) s = 0;
    __syncthreads();
    int bad = 0;
    for (int i = threadIdx.x; i < 2048; i += 256){
      unsigned int e = ((unsigned int)x[2 * i] >> 7) & 0xffu;
      if (e >= 0xF0u) bad = 1;
    }
    if (bad) atomicOr(&s, 1);
    __syncthreads();
    if (threadIdx.x == 0) *flag = s;
  }
  int e = blockIdx.x * 256 + threadIdx.x;
  if (e >= E) return;
  if (e == 0){
    for (int r = 0; r <= rows[0]; ++r) rs[r] = 0;
  } else {
    int a = rows[e - 1], b = rows[e];
    for (int r = a + 1; r <= b; ++r) rs[r] = e;
  }
  if (e == E - 1){
    for (int r = rows[E - 1] + 1; r <= N; ++r) rs[r] = E;
  }
}

// ---- fused transpose of all three W matrices -> canonical bf16 WT ----
__global__ void wtrans_all(const void* __restrict__ Wres,
                           const void* __restrict__ W1,
                           const void* __restrict__ W2,
                           unsigned short* __restrict__ WresT,
                           unsigned short* __restrict__ W1T,
                           unsigned short* __restrict__ W2T,
                           const int* __restrict__ flag){
  int isF32 = *flag;
  int b = blockIdx.x;
  const void* W; unsigned short* WT; int K; int idx;
  if (b < 128)      { W = Wres; WT = WresT; K = 256; idx = b * 256 + threadIdx.x; }
  else if (b < 256) { W = W1;   WT = W1T;   K = 256; idx = (b - 128) * 256 + threadIdx.x; }
  else              { W = W2;   WT = W2T;   K = 128; idx = (b - 256) * 256 + threadIdx.x; }
  if (idx >= K * 128) return;
  int n = idx / K, k = idx - n * K;
  WT[idx] = f2bf(ldf(W, (long)k * 128 + n, isF32));
}

// ============================================================
// Single-plane GEMM: out = A[M][K] @ WT^T (+bias), bf16 out.
// One 32 KB W-tile in LDS (XOR-chunk swizzle), 3 blocks/CU,
// batched A global loads + batched B ds_reads per K-quarter.
// ============================================================
template<int KTILES>
__global__ __launch_bounds__(256, 3) void gemm_tile(
    const void* __restrict__ A,
    const unsigned short* __restrict__ WT,   // [128][K] n-major bf16
    const void* __restrict__ bias,           // [128] or nullptr
    unsigned short* __restrict__ out,        // [M][128] bf16
    int M, const int* __restrict__ flagp, int aFollowsFlag)
{
  constexpr int K = KTILES * 128;
  __shared__ __align__(16) unsigned short lW[128 * 128];   // 32 KB

  const int fl   = *flagp;
  const int aF32 = aFollowsFlag ? fl : 0;
  const int tid  = threadIdx.x;
  const int lane = tid & 63;
  const int wav  = tid >> 6;
  const int l16  = lane & 15;
  const int quad = lane >> 4;
  const int rowBase = blockIdx.x * 128 + wav * 32;

  f32x4 acc[2][8];
#pragma unroll
  for (int s = 0; s < 2; ++s)
#pragma unroll
    for (int nt = 0; nt < 8; ++nt) acc[s][nt] = (f32x4){0.f, 0.f, 0.f, 0.f};

#pragma unroll
  for (int t = 0; t < KTILES; ++t){
    const int kb = t * 128;
    __syncthreads();   // previous-iter readers done
    // stage W tile: 2048 16B-chunks / 256 threads = 8 per thread, swizzled
#pragma unroll
    for (int j = 0; j < 8; ++j){
      int i = tid + j * 256;
      int n = i >> 4, c = i & 15;
      *(short8*)&lW[n * 128 + ((c ^ (n & 7)) * 8)] =
          *(const short8*)&WT[n * K + kb + c * 8];
    }
    // batched A loads (16 in flight), then convert
    short8 af[2][4];
    if (aF32){
      f32x4 ta[2][8];
#pragma unroll
      for (int s = 0; s < 2; ++s){
        int r = rowBase + s * 16 + l16;
#pragma unroll
        for (int p = 0; p < 8; ++p) ta[s][p] = (f32x4){0.f, 0.f, 0.f, 0.f};
        if (r < M){
          const float* Af = (const float*)A + (long)r * K + kb + quad * 8;
#pragma unroll
          for (int p = 0; p < 8; ++p)
            ta[s][p] = *(const f32x4*)(Af + (p >> 1) * 32 + (p & 1) * 4);
        }
      }
#pragma unroll
      for (int s = 0; s < 2; ++s)
#pragma unroll
        for (int q = 0; q < 4; ++q){
          f32x4 lo = ta[s][2 * q], hi = ta[s][2 * q + 1];
          short8 v;
          v[0] = (short)f2bf(lo[0]); v[1] = (short)f2bf(lo[1]);
          v[2] = (short)f2bf(lo[2]); v[3] = (short)f2bf(lo[3]);
          v[4] = (short)f2bf(hi[0]); v[5] = (short)f2bf(hi[1]);
          v[6] = (short)f2bf(hi[2]); v[7] = (short)f2bf(hi[3]);
          af[s][q] = v;
        }
    } else {
#pragma unroll
      for (int s = 0; s < 2; ++s){
        int r = rowBase + s * 16 + l16;
#pragma unroll
        for (int q = 0; q < 4; ++q) af[s][q] = (short8){};
        if (r < M){
          const unsigned short* Ab = (const unsigned short*)A + (long)r * K + kb + quad * 8;
#pragma unroll
          for (int q = 0; q < 4; ++q) af[s][q] = *(const short8*)(Ab + q * 32);
        }
      }
    }
    __syncthreads();   // staging complete
#pragma unroll
    for (int q = 0; q < 4; ++q){
      short8 bq[8];
#pragma unroll
      for (int nt = 0; nt < 8; ++nt){
        int row = nt * 16 + l16;
        bq[nt] = *(const short8*)&lW[row * 128 + (((q * 4 + quad) ^ (row & 7)) * 8)];
      }
#pragma unroll
      for (int nt = 0; nt < 8; ++nt){
        acc[0][nt] = __builtin_amdgcn_mfma_f32_16x16x32_bf16(af[0][q], bq[nt], acc[0][nt], 0, 0, 0);
        acc[1][nt] = __builtin_amdgcn_mfma_f32_16x16x32_bf16(af[1][q], bq[nt], acc[1][nt], 0, 0, 0);
      }
    }
  }

#pragma unroll
  for (int s = 0; s < 2; ++s){
    int r0 = rowBase + s * 16 + quad * 4;
#pragma unroll
    for (int nt = 0; nt < 8; ++nt){
      int col = nt * 16 + l16;
      float bv = bias ? ldf(bias, col, fl) : 0.0f;
#pragma unroll
      for (int rg = 0; rg < 4; ++rg){
        int r = r0 + rg;
        if (r < M) out[(long)r * 128 + col] = f2bf(acc[s][nt][rg] + bv);
      }
    }
  }
}

// ============================================================
// Dual-row gather with 2-deep software pipeline: chunk n+1's
// col/val loads + gathers issue before chunk n's FMA chain.
// Banks are statically indexed (no scratch). Clamped tails.
// ============================================================
template<int FL>
__device__ __forceinline__ void row_gather_pipe(
    int e0a, int e1a, int e0b, int e1b,
    const int* __restrict__ cols, const void* __restrict__ vals,
    const unsigned short* __restrict__ Y, int lane,
    float& oxa, float& oya, float& oxb, float& oyb)
{
  float axa0 = 0.f, aya0 = 0.f, axa1 = 0.f, aya1 = 0.f;
  float axb0 = 0.f, ayb0 = 0.f, axb1 = 0.f, ayb1 = 0.f;
  const int na = e1a - e0a, nb = e1b - e0b;
  const int nmax = na > nb ? na : nb;
  oxa = oya = oxb = oyb = 0.f;
  if (nmax <= 0) return;
  const int nch = (nmax + 7) >> 3;
  const int ca1 = e1a - 1, cb1 = e1b - 1;
  const unsigned short* Yl = Y + 2 * lane;

  unsigned int qa_0[8], qb_0[8]; float fa_0[8], fb_0[8];
  unsigned int qa_1[8], qb_1[8]; float fa_1[8], fb_1[8];

#define LOADCH(SUF, CH) do {                                                   \
    const int base_ = (CH) * 8;                                                \
    _Pragma("unroll")                                                          \
    for (int i_ = 0; i_ < 8; ++i_){                                            \
      int ea_ = e0a + base_ + i_;                                              \
      int ec_ = ea_ < ca1 ? ea_ : ca1; ec_ = ec_ > 0 ? ec_ : 0;                \
      int eb_ = e0b + base_ + i_;                                              \
      int ed_ = eb_ < cb1 ? eb_ : cb1; ed_ = ed_ > 0 ? ed_ : 0;                \
      int ca_ = cols[ec_];                                                     \
      int cb_ = cols[ed_];                                                     \
      float va_ = FL ? ((const float*)vals)[ec_]                               \
                     : bf2f(((const unsigned short*)vals)[ec_]);               \
      float vb_ = FL ? ((const float*)vals)[ed_]                               \
                     : bf2f(((const unsigned short*)vals)[ed_]);               \
      fa_##SUF[i_] = (ea_ < e1a) ? va_ : 0.f;                                  \
      fb_##SUF[i_] = (eb_ < e1b) ? vb_ : 0.f;                                  \
      qa_##SUF[i_] = *(const unsigned int*)(Yl + (long)ca_ * 128);             \
      qb_##SUF[i_] = *(const unsigned int*)(Yl + (long)cb_ * 128);             \
    }                                                                          \
  } while (0)

#define FMACH(SUF) do {                                                        \
    _Pragma("unroll")                                                          \
    for (int i_ = 0; i_ < 8; ++i_){                                            \
      float yla_ = bf2f((unsigned short)(qa_##SUF[i_] & 0xffffu));             \
      float yha_ = bf2f((unsigned short)(qa_##SUF[i_] >> 16));                 \
      float ylb_ = bf2f((unsigned short)(qb_##SUF[i_] & 0xffffu));             \
      float yhb_ = bf2f((unsigned short)(qb_##SUF[i_] >> 16));                 \
      if (i_ & 1){                                                             \
        axa1 = fmaf(fa_##SUF[i_], yla_, axa1);                                 \
        aya1 = fmaf(fa_##SUF[i_], yha_, aya1);                                 \
        axb1 = fmaf(fb_##SUF[i_], ylb_, axb1);                                 \
        ayb1 = fmaf(fb_##SUF[i_], yhb_, ayb1);                                 \
      } else {                                                                 \
        axa0 = fmaf(fa_##SUF[i_], yla_, axa0);                                 \
        aya0 = fmaf(fa_##SUF[i_], yha_, aya0);                                 \
        axb0 = fmaf(fb_##SUF[i_], ylb_, axb0);                                 \
        ayb0 = fmaf(fb_##SUF[i_], yhb_, ayb0);                                 \
      }                                                                        \
    }                                                                          \
  } while (0)

  LOADCH(0, 0);
  int ch = 0;
  for (;;){
    if (ch + 1 < nch) LOADCH(1, ch + 1);
    FMACH(0);
    ++ch; if (ch >= nch) break;
    if (ch + 1 < nch) LOADCH(0, ch + 1);
    FMACH(1);
    ++ch; if (ch >= nch) break;
  }
#undef LOADCH
#undef FMACH

  oxa = (axa0 + axa1); oya = (aya0 + aya1);
  oxb = (axb0 + axb1); oyb = (ayb0 + ayb1);
}

// ---- spmm1 fused: x1[r] = relu(spmm(y1)[r] + b1) + z[r], 2 rows/wave ----
__global__ __launch_bounds__(256) void spmm1_f(
    const int* __restrict__ rs, const int* __restrict__ cols,
    const void* __restrict__ vals, const unsigned short* __restrict__ Y,
    const unsigned short* __restrict__ z, const void* __restrict__ b1,
    unsigned short* __restrict__ x1, int N, const int* __restrict__ flagp)
{
  const int fl   = *flagp;
  const int lane = threadIdx.x & 63;
  const int wav  = threadIdx.x >> 6;
  int ra = blockIdx.x * 8 + wav * 2;
  if (ra >= N) return;
  int rb = ra + 1;
  bool hasB = rb < N;
  int e0a = __builtin_amdgcn_readfirstlane(rs[ra]);
  int e1a = __builtin_amdgcn_readfirstlane(rs[ra + 1]);
  int e0b = e1a, e1b = e1a;
  if (hasB) e1b = __builtin_amdgcn_readfirstlane(rs[rb + 1]);
  float axa, aya, axb, ayb;
  if (fl) row_gather_pipe<1>(e0a, e1a, e0b, e1b, cols, vals, Y, lane, axa, aya, axb, ayb);
  else    row_gather_pipe<0>(e0a, e1a, e0b, e1b, cols, vals, Y, lane, axa, aya, axb, ayb);
  float b0 = ldf(b1, 2 * lane, fl), b1v = ldf(b1, 2 * lane + 1, fl);
  long oa = (long)ra * 128 + 2 * lane;
  unsigned int za = *(const unsigned int*)&z[oa];
  float r0 = fmaxf(axa + b0,  0.f) + bf2f((unsigned short)(za & 0xffffu));
  float r1 = fmaxf(aya + b1v, 0.f) + bf2f((unsigned short)(za >> 16));
  *(unsigned int*)&x1[oa] = (unsigned int)f2bf(r0) | ((unsigned int)f2bf(r1) << 16);
  if (hasB){
    long ob = oa + 128;
    unsigned int zb = *(const unsigned int*)&z[ob];
    float s0 = fmaxf(axb + b0,  0.f) + bf2f((unsigned short)(zb & 0xffffu));
    float s1 = fmaxf(ayb + b1v, 0.f) + bf2f((unsigned short)(zb >> 16));
    *(unsigned int*)&x1[ob] = (unsigned int)f2bf(s0) | ((unsigned int)f2bf(s1) << 16);
  }
}

// ---- spmm2 fused: out[r] = log_softmax(spmm(y2)[r] + b2), 2 rows/wave ----
__global__ __launch_bounds__(256) void spmm2_f(
    const int* __restrict__ rs, const int* __restrict__ cols,
    const void* __restrict__ vals, const unsigned short* __restrict__ Y,
    const void* __restrict__ b2, void* __restrict__ out, int N,
    const int* __restrict__ flagp)
{
  const int fl   = *flagp;
  const int lane = threadIdx.x & 63;
  const int wav  = threadIdx.x >> 6;
  int ra = blockIdx.x * 8 + wav * 2;
  if (ra >= N) return;
  int rb = ra + 1;
  bool hasB = rb < N;
  int e0a = __builtin_amdgcn_readfirstlane(rs[ra]);
  int e1a = __builtin_amdgcn_readfirstlane(rs[ra + 1]);
  int e0b = e1a, e1b = e1a;
  if (hasB) e1b = __builtin_amdgcn_readfirstlane(rs[rb + 1]);
  float axa, aya, axb, ayb;
  if (fl) row_gather_pipe<1>(e0a, e1a, e0b, e1b, cols, vals, Y, lane, axa, aya, axb, ayb);
  else    row_gather_pipe<0>(e0a, e1a, e0b, e1b, cols, vals, Y, lane, axa, aya, axb, ayb);
  float bb0 = ldf(b2, 2 * lane, fl), bb1 = ldf(b2, 2 * lane + 1, fl);
  float v0a = axa + bb0, v1a = aya + bb1;
  float v0b = axb + bb0, v1b = ayb + bb1;
  float ma = fmaxf(v0a, v1a), mb = fmaxf(v0b, v1b);
#pragma unroll
  for (int off = 32; off; off >>= 1){
    ma = fmaxf(ma, __shfl_xor(ma, off));
    mb = fmaxf(mb, __shfl_xor(mb, off));
  }
  float sa = expf(v0a - ma) + expf(v1a - ma);
  float sb = expf(v0b - mb) + expf(v1b - mb);
#pragma unroll
  for (int off = 32; off; off >>= 1){
    sa += __shfl_xor(sa, off);
    sb += __shfl_xor(sb, off);
  }
  float lsea = ma + logf(sa);
  float lseb = mb + logf(sb);
  long oa = (long)ra * 128 + 2 * lane;
  if (fl){
    float2 wa; wa.x = v0a - lsea; wa.y = v1a - lsea;
    *(float2*)&((float*)out)[oa] = wa;
    if (hasB){
      float2 wb; wb.x = v0b - lseb; wb.y = v1b - lseb;
      *(float2*)&((float*)out)[oa + 128] = wb;
    }
  } else {
    *(unsigned int*)&((unsigned short*)out)[oa] =
        (unsigned int)f2bf(v0a - lsea) | ((unsigned int)f2bf(v1a - lsea) << 16);
    if (hasB){
      *(unsigned int*)&((unsigned short*)out)[oa + 128] =
          (unsigned int)f2bf(v0b - lseb) | ((unsigned int)f2bf(v1b - lseb) << 16);
    }
  }
}

extern "C" void kernel_launch(void* const* d_in, const int* in_sizes, int n_in,
                              void* d_out, int out_size, void* d_ws, size_t ws_size,
                              hipStream_t stream)
{
  const void* x    = d_in[0];
  const int*  erow = (const int*)d_in[1];
  const int*  ecol = (const int*)d_in[2];
  const void* eval = d_in[3];
  const void* Wres = d_in[4];
  const void* bres = d_in[5];
  const void* W1   = d_in[6];
  const void* b1   = d_in[7];
  const void* W2   = d_in[8];
  const void* b2   = d_in[9];
  const int N = in_sizes[0] / 256;   // 100000
  const int E = in_sizes[1];         // 1600000

  char* ws = (char*)d_ws;
  size_t szB = (size_t)N * 128 * 2;  // one bf16 [N,128] plane (25.6 MB)
  unsigned short* bufA  = (unsigned short*)ws;            // y1, then y2
  unsigned short* bufC  = (unsigned short*)(ws + szB);    // x1
  unsigned short* WresT = (unsigned short*)(ws + 2 * szB);
  unsigned short* W1T   = WresT + 256 * 128;
  unsigned short* W2T   = W1T   + 256 * 128;
  int*            flag  = (int*)(W2T + 256 * 128);
  int*            rs    = flag + 4;                        // [N+1] row_ptr
  unsigned short* zbuf  = (unsigned short*)d_out;          // z (bf16) in d_out

  prep_k<<<(E + 255) / 256, 256, 0, stream>>>(erow, rs, E, N,
                                              (const unsigned short*)x, flag);
  wtrans_all<<<320, 256, 0, stream>>>(Wres, W1, W2, WresT, W1T, W2T, flag);

  const int gBlocks = (N + 127) / 128;
  const int rBlocks = (N + 7) / 8;

  gemm_tile<2><<<gBlocks, 256, 0, stream>>>(x, WresT, bres, zbuf, N, flag, 1);   // z
  gemm_tile<2><<<gBlocks, 256, 0, stream>>>(x, W1T, nullptr, bufA, N, flag, 1);  // y1

  spmm1_f<<<rBlocks, 256, 0, stream>>>(rs, ecol, eval, bufA, zbuf, b1, bufC, N, flag); // x1

  gemm_tile<1><<<gBlocks, 256, 0, stream>>>(bufC, W2T, nullptr, bufA, N, flag, 0);     // y2

  spmm2_f<<<rBlocks, 256, 0, stream>>>(rs, ecol, eval, bufA, b2, d_out, N, flag);      // out
}